// Round 6
// baseline (637.689 us; speedup 1.0000x reference)
//
#include <hip/hip_runtime.h>
#include <math.h>

// HyperbolicGraphConvolution on MI355X.
// N=100000 nodes, D=65 (col 0 identically 0 through GCN hops -> propagate 64),
// E=1.6M edges. CSR built per call (histogram + multi-block scan + scatter of
// PACKED int2 {col, val}), then 3 gather SpMMs: one wave per row, lane d =
// feature d, edges broadcast via shfl, zero atomics in hot loop. 3-hop
// accumulator lives in d_out cols 1..64.

__device__ __forceinline__ float waveReduceSum(float v) {
  #pragma unroll
  for (int m = 32; m > 0; m >>= 1) v += __shfl_xor(v, m, 64);
  return v;
}

// t[i,d] = acosh(max(x[i,0], 1+1e-7)) * y_d / max(||y||, 1e-15), y = x[i,1:65]
__global__ __launch_bounds__(256) void k_logmap0(const float* __restrict__ x,
                                                 float* __restrict__ t, int n) {
  int wid = (blockIdx.x * blockDim.x + threadIdx.x) >> 6;
  int lane = threadIdx.x & 63;
  if (wid >= n) return;
  const float* row = x + (size_t)wid * 65;
  float x0 = row[0];
  float y = row[1 + lane];
  float ss = waveReduceSum(y * y);
  float nrm = fmaxf(sqrtf(ss), 1e-15f);
  float theta = fmaxf(x0, 1.0f + 1e-7f);
  t[(size_t)wid * 64 + lane] = acoshf(theta) * (y / nrm);
}

__global__ void k_hist(const int* __restrict__ rows, int* __restrict__ cnt, int e) {
  int i = blockIdx.x * blockDim.x + threadIdx.x;
  int stride = gridDim.x * blockDim.x;
  for (; i < e; i += stride) atomicAdd(&cnt[rows[i]], 1);
}

// ---- 3-phase multi-block exclusive scan over cnt[0..n) ----
__global__ __launch_bounds__(1024) void k_scan1(const int* __restrict__ cnt,
                                                int* __restrict__ off,
                                                int* __restrict__ bsum, int n) {
  __shared__ int sh[1024];
  int i = blockIdx.x * 1024 + threadIdx.x;
  int v = (i < n) ? cnt[i] : 0;
  sh[threadIdx.x] = v;
  __syncthreads();
  #pragma unroll
  for (int d = 1; d < 1024; d <<= 1) {
    int t = (threadIdx.x >= d) ? sh[threadIdx.x - d] : 0;
    __syncthreads();
    sh[threadIdx.x] += t;
    __syncthreads();
  }
  if (i < n) off[i] = sh[threadIdx.x] - v;
  if (threadIdx.x == 1023) bsum[blockIdx.x] = sh[1023];
}

__global__ __launch_bounds__(1024) void k_scan2(int* __restrict__ bsum, int nb) {
  __shared__ int sh[1024];
  int v = (threadIdx.x < nb) ? bsum[threadIdx.x] : 0;
  sh[threadIdx.x] = v;
  __syncthreads();
  #pragma unroll
  for (int d = 1; d < 1024; d <<= 1) {
    int t = (threadIdx.x >= d) ? sh[threadIdx.x - d] : 0;
    __syncthreads();
    sh[threadIdx.x] += t;
    __syncthreads();
  }
  if (threadIdx.x < nb) bsum[threadIdx.x] = sh[threadIdx.x] - v;
}

__global__ __launch_bounds__(1024) void k_scan3(int* __restrict__ off,
                                                const int* __restrict__ bsum,
                                                int* __restrict__ cursor,
                                                int n, int e) {
  int i = blockIdx.x * 1024 + threadIdx.x;
  if (i < n) {
    int o = off[i] + bsum[blockIdx.x];
    off[i] = o;
    cursor[i] = o;
  }
  if (i == 0) off[n] = e;
}

// One packed 8B store per edge (col + bitcast val) -> halves scattered lines
// vs two 4B stores to separate arrays.
__global__ void k_scatter(const int* __restrict__ rows, const int* __restrict__ cols,
                          const float* __restrict__ vals, int* __restrict__ cursor,
                          int2* __restrict__ ev, int e) {
  int i = blockIdx.x * blockDim.x + threadIdx.x;
  int stride = gridDim.x * blockDim.x;
  for (; i < e; i += stride) {
    int r = rows[i];
    int p = atomicAdd(&cursor[r], 1);
    ev[p] = make_int2(cols[i], __float_as_int(vals[i]));
  }
}

// One wave per row: lane d accumulates feature d over the row's edge bucket.
// Packed edges loaded coalesced 64-at-a-time (8B/lane), broadcast via shfl.
// acc points into d_out (stride 65, cols 1..64) and accumulates the 3 hops.
__global__ __launch_bounds__(256) void k_spmm(const int* __restrict__ off,
                                              const int2* __restrict__ ev,
                                              const float* __restrict__ hin,
                                              float* __restrict__ hout,
                                              float* __restrict__ acc,
                                              int n, int first) {
  int wid = (blockIdx.x * blockDim.x + threadIdx.x) >> 6;
  int lane = threadIdx.x & 63;
  if (wid >= n) return;
  int s = off[wid], e = off[wid + 1];
  float a = 0.f;
  for (int base = s; base < e; base += 64) {
    int idx = base + lane;
    int2 cv = (idx < e) ? ev[idx] : make_int2(0, 0);
    int m = min(64, e - base);
    #pragma unroll 8
    for (int j = 0; j < m; ++j) {
      int cj = __shfl(cv.x, j, 64);
      float vj = __int_as_float(__shfl(cv.y, j, 64));
      a += vj * hin[(size_t)cj * 64 + lane];
    }
  }
  hout[(size_t)wid * 64 + lane] = a;
  float* ap = acc + (size_t)wid * 65 + 1 + lane;
  if (first) *ap = a;
  else *ap += a;
}

// acc (in d_out cols 1..64) -> out = [sqrt(max(1+||tail||^2, 1e-7)), tail],
// tail = sinh(nrm)/nrm * acc, nrm = max(||acc||, 1e-15)
__global__ __launch_bounds__(256) void k_final(float* __restrict__ out, int n) {
  int wid = (blockIdx.x * blockDim.x + threadIdx.x) >> 6;
  int lane = threadIdx.x & 63;
  if (wid >= n) return;
  float* row = out + (size_t)wid * 65;
  float a = row[1 + lane];
  float ss = waveReduceSum(a * a);
  float nrm = fmaxf(sqrtf(ss), 1e-15f);
  float sh = sinhf(nrm) / nrm;
  float tl = sh * a;
  float ss2 = waveReduceSum(tl * tl);
  float first = sqrtf(fmaxf(1.0f + ss2, 1e-7f));
  row[1 + lane] = tl;
  if (lane == 0) row[0] = first;
}

extern "C" void kernel_launch(void* const* d_in, const int* in_sizes, int n_in,
                              void* d_out, int out_size, void* d_ws, size_t ws_size,
                              hipStream_t stream) {
  const float* x = (const float*)d_in[0];
  const int* rows = (const int*)d_in[1];
  const int* cols = (const int*)d_in[2];
  const float* vals = (const float*)d_in[3];
  float* out = (float*)d_out;
  int n = in_sizes[0] / 65;
  int e = in_sizes[1];

  // workspace layout (~65 MB total)
  char* w = (char*)d_ws;
  auto alloc = [&](size_t bytes) {
    void* p = (void*)w;
    w += (bytes + 255) & ~(size_t)255;
    return p;
  };
  int* cnt  = (int*)alloc((size_t)n * 4);            // histogram -> cursor
  int* off  = (int*)alloc(((size_t)n + 1) * 4);      // CSR row offsets
  int* bsum = (int*)alloc(1024 * 4);                 // scan block sums
  int2* ev  = (int2*)alloc((size_t)e * 8);           // packed bucketed edges
  float* h0 = (float*)alloc((size_t)n * 64 * 4);     // ping
  float* h1 = (float*)alloc((size_t)n * 64 * 4);     // pong

  hipMemsetAsync(cnt, 0, (size_t)n * 4, stream);

  int nwb = (n + 3) / 4;           // 4 waves (rows) per 256-thread block
  int nsb = (n + 1023) / 1024;     // scan blocks (98 for n=100000)

  k_logmap0<<<nwb, 256, 0, stream>>>(x, h0, n);
  k_hist<<<2048, 256, 0, stream>>>(rows, cnt, e);
  k_scan1<<<nsb, 1024, 0, stream>>>(cnt, off, bsum, n);
  k_scan2<<<1, 1024, 0, stream>>>(bsum, nsb);
  k_scan3<<<nsb, 1024, 0, stream>>>(off, bsum, cnt, n, e);
  k_scatter<<<2048, 256, 0, stream>>>(rows, cols, vals, cnt, ev, e);

  k_spmm<<<nwb, 256, 0, stream>>>(off, ev, h0, h1, out, n, 1);
  k_spmm<<<nwb, 256, 0, stream>>>(off, ev, h1, h0, out, n, 0);
  k_spmm<<<nwb, 256, 0, stream>>>(off, ev, h0, h1, out, n, 0);

  k_final<<<nwb, 256, 0, stream>>>(out, n);
}

// Round 8
// 590.606 us; speedup vs baseline: 1.0797x; 1.0797x over previous
//
#include <hip/hip_runtime.h>
#include <math.h>

// HyperbolicGraphConvolution on MI355X.
// N=100000 nodes, D=65 (col 0 identically 0 through GCN hops -> propagate 64),
// E=1.6M edges. CSR built per call. k_scatter is XCD-partitioned by destination
// row range (blockIdx&7 ~ XCD under default round-robin mapping): each range's
// CSR region (1.6MB) is written by one XCD only -> partial-line cross-XCD
// writebacks (the 8x WRITE_SIZE amplification seen in r6) collapse to 1x.
// Then 3 gather SpMMs: one wave per row, lane d = feature d, edges broadcast
// via shfl, zero atomics in hot loop. 3-hop accumulator in d_out cols 1..64.

__device__ __forceinline__ float waveReduceSum(float v) {
  #pragma unroll
  for (int m = 32; m > 0; m >>= 1) v += __shfl_xor(v, m, 64);
  return v;
}

// t[i,d] = acosh(max(x[i,0], 1+1e-7)) * y_d / max(||y||, 1e-15), y = x[i,1:65]
__global__ __launch_bounds__(256) void k_logmap0(const float* __restrict__ x,
                                                 float* __restrict__ t, int n) {
  int wid = (blockIdx.x * blockDim.x + threadIdx.x) >> 6;
  int lane = threadIdx.x & 63;
  if (wid >= n) return;
  const float* row = x + (size_t)wid * 65;
  float x0 = row[0];
  float y = row[1 + lane];
  float ss = waveReduceSum(y * y);
  float nrm = fmaxf(sqrtf(ss), 1e-15f);
  float theta = fmaxf(x0, 1.0f + 1e-7f);
  t[(size_t)wid * 64 + lane] = acoshf(theta) * (y / nrm);
}

__global__ void k_hist(const int* __restrict__ rows, int* __restrict__ cnt, int e) {
  int i = blockIdx.x * blockDim.x + threadIdx.x;
  int stride = gridDim.x * blockDim.x;
  for (; i < e; i += stride) atomicAdd(&cnt[rows[i]], 1);
}

// ---- 3-phase multi-block exclusive scan over cnt[0..n) ----
__global__ __launch_bounds__(1024) void k_scan1(const int* __restrict__ cnt,
                                                int* __restrict__ off,
                                                int* __restrict__ bsum, int n) {
  __shared__ int sh[1024];
  int i = blockIdx.x * 1024 + threadIdx.x;
  int v = (i < n) ? cnt[i] : 0;
  sh[threadIdx.x] = v;
  __syncthreads();
  #pragma unroll
  for (int d = 1; d < 1024; d <<= 1) {
    int t = (threadIdx.x >= d) ? sh[threadIdx.x - d] : 0;
    __syncthreads();
    sh[threadIdx.x] += t;
    __syncthreads();
  }
  if (i < n) off[i] = sh[threadIdx.x] - v;
  if (threadIdx.x == 1023) bsum[blockIdx.x] = sh[1023];
}

__global__ __launch_bounds__(1024) void k_scan2(int* __restrict__ bsum, int nb) {
  __shared__ int sh[1024];
  int v = (threadIdx.x < nb) ? bsum[threadIdx.x] : 0;
  sh[threadIdx.x] = v;
  __syncthreads();
  #pragma unroll
  for (int d = 1; d < 1024; d <<= 1) {
    int t = (threadIdx.x >= d) ? sh[threadIdx.x - d] : 0;
    __syncthreads();
    sh[threadIdx.x] += t;
    __syncthreads();
  }
  if (threadIdx.x < nb) bsum[threadIdx.x] = sh[threadIdx.x] - v;
}

__global__ __launch_bounds__(1024) void k_scan3(int* __restrict__ off,
                                                const int* __restrict__ bsum,
                                                int* __restrict__ cursor,
                                                int n, int e) {
  int i = blockIdx.x * 1024 + threadIdx.x;
  if (i < n) {
    int o = off[i] + bsum[blockIdx.x];
    off[i] = o;
    cursor[i] = o;
  }
  if (i == 0) off[n] = e;
}

// XCD-partitioned scatter: group g = blockIdx&7 handles destination rows
// [g*step, (g+1)*step). Under default round-robin block->XCD mapping, all
// writes to a CSR region come from one XCD; its 1.6MB region fits the 4MB
// per-XCD L2, so lines fill completely and write back once. Correct under
// ANY block->XCD mapping (all 8 residues exist in the grid).
__global__ __launch_bounds__(256) void k_scatter(const int* __restrict__ rows,
                                                 const int* __restrict__ cols,
                                                 const float* __restrict__ vals,
                                                 int* __restrict__ cursor,
                                                 int2* __restrict__ ev,
                                                 int e, int step) {
  int g = blockIdx.x & 7;
  int k = blockIdx.x >> 3;
  int tid = k * blockDim.x + threadIdx.x;
  int nthr = (gridDim.x >> 3) * blockDim.x;
  int rlo = g * step, rhi = rlo + step;
  for (int i = tid; i < e; i += nthr) {
    int r = rows[i];
    if (r >= rlo && r < rhi) {
      int p = atomicAdd(&cursor[r], 1);
      ev[p] = make_int2(cols[i], __float_as_int(vals[i]));
    }
  }
}

// One wave per row: lane d accumulates feature d over the row's edge bucket.
// Packed edges loaded coalesced (8B/lane), broadcast via shfl.
// acc points into d_out (stride 65, cols 1..64), accumulates the 3 hops.
// last=1 skips the dead hout store on the final hop.
__global__ __launch_bounds__(256) void k_spmm(const int* __restrict__ off,
                                              const int2* __restrict__ ev,
                                              const float* __restrict__ hin,
                                              float* __restrict__ hout,
                                              float* __restrict__ acc,
                                              int n, int first, int last) {
  int wid = (blockIdx.x * blockDim.x + threadIdx.x) >> 6;
  int lane = threadIdx.x & 63;
  if (wid >= n) return;
  int s = off[wid], e = off[wid + 1];
  float a = 0.f;
  for (int base = s; base < e; base += 64) {
    int idx = base + lane;
    int2 cv = (idx < e) ? ev[idx] : make_int2(0, 0);
    int m = min(64, e - base);
    #pragma unroll 8
    for (int j = 0; j < m; ++j) {
      int cj = __shfl(cv.x, j, 64);
      float vj = __int_as_float(__shfl(cv.y, j, 64));
      a += vj * hin[(size_t)cj * 64 + lane];
    }
  }
  if (!last) hout[(size_t)wid * 64 + lane] = a;
  float* ap = acc + (size_t)wid * 65 + 1 + lane;
  if (first) *ap = a;
  else *ap += a;
}

// acc (in d_out cols 1..64) -> out = [sqrt(max(1+||tail||^2, 1e-7)), tail],
// tail = sinh(nrm)/nrm * acc, nrm = max(||acc||, 1e-15)
__global__ __launch_bounds__(256) void k_final(float* __restrict__ out, int n) {
  int wid = (blockIdx.x * blockDim.x + threadIdx.x) >> 6;
  int lane = threadIdx.x & 63;
  if (wid >= n) return;
  float* row = out + (size_t)wid * 65;
  float a = row[1 + lane];
  float ss = waveReduceSum(a * a);
  float nrm = fmaxf(sqrtf(ss), 1e-15f);
  float sh = sinhf(nrm) / nrm;
  float tl = sh * a;
  float ss2 = waveReduceSum(tl * tl);
  float first = sqrtf(fmaxf(1.0f + ss2, 1e-7f));
  row[1 + lane] = tl;
  if (lane == 0) row[0] = first;
}

extern "C" void kernel_launch(void* const* d_in, const int* in_sizes, int n_in,
                              void* d_out, int out_size, void* d_ws, size_t ws_size,
                              hipStream_t stream) {
  const float* x = (const float*)d_in[0];
  const int* rows = (const int*)d_in[1];
  const int* cols = (const int*)d_in[2];
  const float* vals = (const float*)d_in[3];
  float* out = (float*)d_out;
  int n = in_sizes[0] / 65;
  int e = in_sizes[1];

  // workspace layout (~65 MB total)
  char* w = (char*)d_ws;
  auto alloc = [&](size_t bytes) {
    void* p = (void*)w;
    w += (bytes + 255) & ~(size_t)255;
    return p;
  };
  int* cnt  = (int*)alloc((size_t)n * 4);            // histogram -> cursor
  int* off  = (int*)alloc(((size_t)n + 1) * 4);      // CSR row offsets
  int* bsum = (int*)alloc(1024 * 4);                 // scan block sums
  int2* ev  = (int2*)alloc((size_t)e * 8);           // packed bucketed edges
  float* h0 = (float*)alloc((size_t)n * 64 * 4);     // ping
  float* h1 = (float*)alloc((size_t)n * 64 * 4);     // pong

  hipMemsetAsync(cnt, 0, (size_t)n * 4, stream);

  int nwb = (n + 3) / 4;           // 4 waves (rows) per 256-thread block
  int nsb = (n + 1023) / 1024;     // scan blocks (98 for n=100000)
  int step = (n + 7) / 8;          // rows per XCD partition

  k_logmap0<<<nwb, 256, 0, stream>>>(x, h0, n);
  k_hist<<<2048, 256, 0, stream>>>(rows, cnt, e);
  k_scan1<<<nsb, 1024, 0, stream>>>(cnt, off, bsum, n);
  k_scan2<<<1, 1024, 0, stream>>>(bsum, nsb);
  k_scan3<<<nsb, 1024, 0, stream>>>(off, bsum, cnt, n, e);
  k_scatter<<<2048, 256, 0, stream>>>(rows, cols, vals, cnt, ev, e, step);

  k_spmm<<<nwb, 256, 0, stream>>>(off, ev, h0, h1, out, n, 1, 0);
  k_spmm<<<nwb, 256, 0, stream>>>(off, ev, h1, h0, out, n, 0, 0);
  k_spmm<<<nwb, 256, 0, stream>>>(off, ev, h0, h1, out, n, 0, 1);

  k_final<<<nwb, 256, 0, stream>>>(out, n);
}